// Round 15
// baseline (558.347 us; speedup 1.0000x reference)
//
#include <hip/hip_runtime.h>
#include <hip/hip_bf16.h>

#define DEV __device__ __forceinline__

static constexpr int Bn = 16;
static constexpr int Cc = 4;
static constexpr int HW = 4096;      // L (=64*64)
static constexpr int BL = Bn * HW;   // 65536 rows
static constexpr int DM = 64;
static constexpr int DI = 128;
static constexpr int NS = 16;        // D_STATE
static constexpr int NC = 256;       // chunks per sequence
static constexpr int CS = HW / NC;   // 16 steps per chunk

DEV float sigmoid_f(float x) { return 1.f / (1.f + __expf(-x)); }
DEV float softplus_f(float x) {
    return fmaxf(x, 0.f) + __logf(1.f + __expf(-fabsf(x)));
}
DEV float silu_f(float x) { return x / (1.f + __expf(-x)); }

// ---------------- embed: feat[b,l,m] = sum_c z[b,c,l]*ew[m,c] + eb[m] ----------
__global__ __launch_bounds__(256) void k_embed(const float* __restrict__ z,
                                               const float* __restrict__ ew,
                                               const float* __restrict__ eb,
                                               float* __restrict__ feat) {
    int idx = blockIdx.x * 256 + threadIdx.x;          // over BL*DM
    if (idx >= BL * DM) return;
    int m = idx & 63;
    int bl = idx >> 6;
    int b = bl >> 12;
    int hw = bl & 4095;
    const float* zp = z + (size_t)b * Cc * HW + hw;
    float acc = eb[m];
#pragma unroll
    for (int c = 0; c < 4; ++c) acc += zp[(size_t)c * HW] * ew[m * 4 + c];
    feat[idx] = acc;
}

// ---------------- layernorm over last dim (64), in place -----------------------
__global__ __launch_bounds__(256) void k_ln(float* __restrict__ feat,
                                            const float* __restrict__ g,
                                            const float* __restrict__ bta, int R) {
    int lane = threadIdx.x & 63;
    int wv = blockIdx.x * 4 + (threadIdx.x >> 6);
    int stride = gridDim.x * 4;
    for (int row = wv; row < R; row += stride) {
        float x = feat[(size_t)row * 64 + lane];
        float s = x;
#pragma unroll
        for (int off = 32; off; off >>= 1) s += __shfl_xor(s, off, 64);
        float mu = s * (1.f / 64.f);
        float xm = x - mu;
        float v = xm * xm;
#pragma unroll
        for (int off = 32; off; off >>= 1) v += __shfl_xor(v, off, 64);
        float var = v * (1.f / 64.f);
        feat[(size_t)row * 64 + lane] = xm * rsqrtf(var + 1e-5f) * g[lane] + bta[lane];
    }
}

// ---- register-tiled GEMM: out[r, n0+c] = sum_k in[r,k] * W[n0+c, k] -----------
// TM=4/TN=4, 256 compute threads, interleaved rows (r = ty + i*16), k4-major
// conflict-free Ws staging. No fused transforms (round-13: fusion cost 144 VGPR
// and halved occupancy — worse than the separate 4-7 µs embed/LN kernels).
template <int K, int BN>
__global__ __launch_bounds__(256) void k_gemm(const float* __restrict__ in,
                                              const float* __restrict__ W,
                                              float* __restrict__ out,
                                              int Nfull) {
    constexpr int BM = 64, TM = 4, TN = 4;
    constexpr int CT = BN / TN;        // 16
    constexpr int RT = BM / TM;        // 16
    constexpr int KP = K + 4;
    constexpr int WP = BN + 4;
    __shared__ float As[BM * KP];
    __shared__ float Ws[K * WP];
    int tid = threadIdx.x;
    int n0 = blockIdx.y * BN;
    int row0 = blockIdx.x * BM;
    // stage W transposed, k4-major (lanes span c -> all banks, conflict-free)
    for (int i = tid; i < BN * (K / 4); i += 256) {
        int k4 = i / BN;
        int c = i - k4 * BN;
        float4 w = *reinterpret_cast<const float4*>(&W[(size_t)(n0 + c) * K + k4 * 4]);
        Ws[(k4 * 4 + 0) * WP + c] = w.x;
        Ws[(k4 * 4 + 1) * WP + c] = w.y;
        Ws[(k4 * 4 + 2) * WP + c] = w.z;
        Ws[(k4 * 4 + 3) * WP + c] = w.w;
    }
    // stage A tile
    for (int i = tid; i < BM * (K / 4); i += 256) {
        int r = i / (K / 4);
        int k4 = i - r * (K / 4);
        *reinterpret_cast<float4*>(&As[r * KP + k4 * 4]) =
            *reinterpret_cast<const float4*>(&in[(size_t)(row0 + r) * K + k4 * 4]);
    }
    __syncthreads();
    // GEMM: thread (ty,tx) owns rows {ty + i*RT} x cols {tx*4..+3}
    int ty = tid / CT, tx = tid - (tid / CT) * CT;
    int c0 = tx * TN;
    float acc[TM][TN];
#pragma unroll
    for (int i = 0; i < TM; ++i)
#pragma unroll
        for (int c = 0; c < TN; ++c) acc[i][c] = 0.f;
    for (int k = 0; k < K; k += 4) {
        float4 a[TM];
#pragma unroll
        for (int i = 0; i < TM; ++i)
            a[i] = *reinterpret_cast<const float4*>(&As[(ty + i * RT) * KP + k]);
        float4 b0 = *reinterpret_cast<const float4*>(&Ws[(k + 0) * WP + c0]);
        float4 b1 = *reinterpret_cast<const float4*>(&Ws[(k + 1) * WP + c0]);
        float4 b2 = *reinterpret_cast<const float4*>(&Ws[(k + 2) * WP + c0]);
        float4 b3 = *reinterpret_cast<const float4*>(&Ws[(k + 3) * WP + c0]);
#pragma unroll
        for (int i = 0; i < TM; ++i) {
            acc[i][0] += a[i].x * b0.x + a[i].y * b1.x + a[i].z * b2.x + a[i].w * b3.x;
            acc[i][1] += a[i].x * b0.y + a[i].y * b1.y + a[i].z * b2.y + a[i].w * b3.y;
            acc[i][2] += a[i].x * b0.z + a[i].y * b1.z + a[i].z * b2.z + a[i].w * b3.z;
            acc[i][3] += a[i].x * b0.w + a[i].y * b1.w + a[i].z * b2.w + a[i].w * b3.w;
        }
    }
#pragma unroll
    for (int i = 0; i < TM; ++i) {
        size_t o = (size_t)(row0 + ty + i * RT) * Nfull + n0 + c0;
        float4 v = {acc[i][0], acc[i][1], acc[i][2], acc[i][3]};
        *reinterpret_cast<float4*>(&out[o]) = v;
    }
}

// ---- x_proj with fused causal conv+SiLU ---------------------------------------
__global__ __launch_bounds__(256) void k_xproj(const float* __restrict__ xz,
                                               const float* __restrict__ W,
                                               const float* __restrict__ cw,
                                               const float* __restrict__ cb,
                                               float* __restrict__ xdbl) {
    constexpr int BM = 64, K = 128, BN = 36, TN = 3, TM = 4;
    constexpr int CT = BN / TN;   // 12
    constexpr int RT = BM / TM;   // 16
    constexpr int KP = K + 4;     // 132
    constexpr int WP = BN + 4;    // 40
    __shared__ float Xs[(BM + 3) * KP];
    __shared__ float Ws[K * WP];
    int tid = threadIdx.x;
    int row0 = blockIdx.x * BM;
    bool first = (row0 & 4095) == 0;
    for (int i = tid; i < BN * (K / 4); i += 256) {
        int k4 = i / BN;
        int c = i - k4 * BN;
        float4 w = *reinterpret_cast<const float4*>(&W[(size_t)c * K + k4 * 4]);
        Ws[(k4 * 4 + 0) * WP + c] = w.x;
        Ws[(k4 * 4 + 1) * WP + c] = w.y;
        Ws[(k4 * 4 + 2) * WP + c] = w.z;
        Ws[(k4 * 4 + 3) * WP + c] = w.w;
    }
    for (int i = tid; i < (BM + 3) * (K / 4); i += 256) {
        int r = i / (K / 4);
        int k4 = i - r * (K / 4);
        float4 v = {0, 0, 0, 0};
        if (!first || r >= 3)
            v = *reinterpret_cast<const float4*>(&xz[(size_t)(row0 - 3 + r) * 256 + k4 * 4]);
        *reinterpret_cast<float4*>(&Xs[r * KP + k4 * 4]) = v;
    }
    __syncthreads();
    {
        int rg = tid >> 5;
        int c0 = (tid & 31) * 4;
        float4 wr[4];
#pragma unroll
        for (int j = 0; j < 4; ++j)
            wr[j] = *reinterpret_cast<const float4*>(&cw[(c0 + j) * 4]);
        float4 cb4 = *reinterpret_cast<const float4*>(&cb[c0]);
        int R0 = rg * 8;
        float4 xr[11];
#pragma unroll
        for (int j = 0; j < 11; ++j)
            xr[j] = *reinterpret_cast<const float4*>(&Xs[(R0 + j) * KP + c0]);
        float4 ur[8];
#pragma unroll
        for (int j = 0; j < 8; ++j) {
            float4 acc;
            acc.x = cb4.x + wr[0].x * xr[j].x + wr[0].y * xr[j + 1].x + wr[0].z * xr[j + 2].x + wr[0].w * xr[j + 3].x;
            acc.y = cb4.y + wr[1].x * xr[j].y + wr[1].y * xr[j + 1].y + wr[1].z * xr[j + 2].y + wr[1].w * xr[j + 3].y;
            acc.z = cb4.z + wr[2].x * xr[j].z + wr[2].y * xr[j + 1].z + wr[2].z * xr[j + 2].z + wr[2].w * xr[j + 3].z;
            acc.w = cb4.w + wr[3].x * xr[j].w + wr[3].y * xr[j + 1].w + wr[3].z * xr[j + 2].w + wr[3].w * xr[j + 3].w;
            ur[j].x = silu_f(acc.x);
            ur[j].y = silu_f(acc.y);
            ur[j].z = silu_f(acc.z);
            ur[j].w = silu_f(acc.w);
        }
        __syncthreads();
#pragma unroll
        for (int j = 0; j < 8; ++j)
            *reinterpret_cast<float4*>(&Xs[(R0 + j) * KP + c0]) = ur[j];
    }
    __syncthreads();
    if (tid < CT * RT) {
        int ty = tid / CT, tx = tid - (tid / CT) * CT;
        int c0 = tx * TN;
        float acc[TM][TN];
#pragma unroll
        for (int i = 0; i < TM; ++i)
#pragma unroll
            for (int c = 0; c < TN; ++c) acc[i][c] = 0.f;
        for (int k = 0; k < K; k += 4) {
            float4 a[TM];
#pragma unroll
            for (int i = 0; i < TM; ++i)
                a[i] = *reinterpret_cast<const float4*>(&Xs[(ty + i * RT) * KP + k]);
            float bv[4][TN];
#pragma unroll
            for (int j = 0; j < 4; ++j)
#pragma unroll
                for (int c = 0; c < TN; ++c) bv[j][c] = Ws[(k + j) * WP + c0 + c];
#pragma unroll
            for (int i = 0; i < TM; ++i)
#pragma unroll
                for (int c = 0; c < TN; ++c)
                    acc[i][c] += a[i].x * bv[0][c] + a[i].y * bv[1][c]
                               + a[i].z * bv[2][c] + a[i].w * bv[3][c];
        }
#pragma unroll
        for (int i = 0; i < TM; ++i) {
            size_t o = (size_t)(row0 + ty + i * RT) * BN + c0;
#pragma unroll
            for (int c = 0; c < TN; ++c) xdbl[o + c] = acc[i][c];
        }
    }
}

// ---- helpers for the scan kernels --------------------------------------------
DEV bool load_a_struct(const float* Alog, int d, float4& a0v, float4& a1v,
                       float4& a2v, float4& a3v, float& a0) {
    const float4* al = reinterpret_cast<const float4*>(Alog + d * NS);
    float4 t0 = al[0], t1 = al[1], t2 = al[2], t3 = al[3];
    a0v.x = -__expf(t0.x); a0v.y = -__expf(t0.y); a0v.z = -__expf(t0.z); a0v.w = -__expf(t0.w);
    a1v.x = -__expf(t1.x); a1v.y = -__expf(t1.y); a1v.z = -__expf(t1.z); a1v.w = -__expf(t1.w);
    a2v.x = -__expf(t2.x); a2v.y = -__expf(t2.y); a2v.z = -__expf(t2.z); a2v.w = -__expf(t2.w);
    a3v.x = -__expf(t3.x); a3v.y = -__expf(t3.y); a3v.z = -__expf(t3.z); a3v.w = -__expf(t3.w);
    a0 = a0v.x;
    float aa[16] = {a0v.x, a0v.y, a0v.z, a0v.w, a1v.x, a1v.y, a1v.z, a1v.w,
                    a2v.x, a2v.y, a2v.z, a2v.w, a3v.x, a3v.y, a3v.z, a3v.w};
    bool fast = true;
#pragma unroll
    for (int n = 0; n < 16; ++n)
        fast = fast && (fabsf(aa[n] - a0 * (float)(n + 1)) <= 1e-4f * (float)(n + 1));
    return fast;
}

#define POWERS(dt, a0, D0, D1, D2, D3)                        \
    {                                                         \
        float E1 = __expf((dt) * (a0));                       \
        float E2 = E1 * E1, E3 = E2 * E1, E4 = E2 * E2;       \
        float E5 = E3 * E2, E6 = E3 * E3, E7 = E4 * E3;       \
        float E8 = E4 * E4, E9 = E5 * E4, E10 = E5 * E5;      \
        float E11 = E6 * E5, E12 = E6 * E6, E13 = E7 * E6;    \
        float E14 = E7 * E7, E15 = E8 * E7, E16 = E8 * E8;    \
        D0 = {E1, E2, E3, E4};                                \
        D1 = {E5, E6, E7, E8};                                \
        D2 = {E9, E10, E11, E12};                             \
        D3 = {E13, E14, E15, E16};                            \
    }

#define UPD4D(H, DA, BV)                          \
    H.x = DA.x * H.x + du * BV.x;                 \
    H.y = DA.y * H.y + du * BV.y;                 \
    H.z = DA.z * H.z + du * BV.z;                 \
    H.w = DA.w * H.w + du * BV.w;

#define UPD4E(H, A, BV)                                  \
    H.x = __expf(dt * A.x) * H.x + du * BV.x;            \
    H.y = __expf(dt * A.y) * H.y + du * BV.y;            \
    H.z = __expf(dt * A.z) * H.z + du * BV.z;            \
    H.w = __expf(dt * A.w) * H.w + du * BV.w;

#define CONV_WARMUP                                                     \
    float x3 = 0.f, x2 = 0.f, x1 = 0.f;                                 \
    if (c != 0) {                                                       \
        size_t wb = ((size_t)b * HW + t0) * 256 + d;                    \
        x3 = xz[wb - 3 * 256];                                          \
        x2 = xz[wb - 2 * 256];                                          \
        x1 = xz[wb - 1 * 256];                                          \
    }

#define CONV_STEP(base)                                                 \
    float xv = xz[(base) * 256 + d];                                    \
    float cacc = cbv + cwv.x * x3 + cwv.y * x2 + cwv.z * x1 + cwv.w * xv; \
    float uu = cacc * sigmoid_f(cacc);                                  \
    x3 = x2; x2 = x1; x1 = xv;

// ---------------- scan pass 1: per-chunk local scan (h0 = 0) -------------------
__global__ __launch_bounds__(128, 4) void k_scan1(const float* __restrict__ xz,
                                                  const float* __restrict__ xdbl,
                                                  const float* __restrict__ dpw,
                                                  const float* __restrict__ dpb,
                                                  const float* __restrict__ Alog,
                                                  const float* __restrict__ cw,
                                                  const float* __restrict__ cb,
                                                  float* __restrict__ cS,
                                                  float* __restrict__ cDT) {
    int blk = blockIdx.x;
    int b = blk / NC;
    int c = blk % NC;
    int d = threadIdx.x;
    float4 a0v, a1v, a2v, a3v;
    float a0;
    bool fast = load_a_struct(Alog, d, a0v, a1v, a2v, a3v, a0);
    float4 w = *reinterpret_cast<const float4*>(dpw + d * 4);
    float bb = dpb[d];
    float4 cwv = *reinterpret_cast<const float4*>(cw + d * 4);
    float cbv = cb[d];
    float4 h0 = {0, 0, 0, 0}, h1 = {0, 0, 0, 0}, h2 = {0, 0, 0, 0}, h3 = {0, 0, 0, 0};
    float sdt = 0.f;
    int t0 = c * CS;
    CONV_WARMUP
    if (fast) {
        for (int tt = 0; tt < CS; ++tt) {
            size_t base = (size_t)b * HW + t0 + tt;
            const float4* xd4 = reinterpret_cast<const float4*>(xdbl + base * 36);
            float4 x0 = xd4[0];
            float4 B0 = xd4[1], B1 = xd4[2], B2 = xd4[3], B3 = xd4[4];
            float dt = softplus_f(w.x * x0.x + w.y * x0.y + w.z * x0.z + w.w * x0.w + bb);
            CONV_STEP(base)
            float du = dt * uu;
            sdt += dt;
            float4 D0, D1, D2, D3;
            POWERS(dt, a0, D0, D1, D2, D3)
            UPD4D(h0, D0, B0) UPD4D(h1, D1, B1) UPD4D(h2, D2, B2) UPD4D(h3, D3, B3)
        }
    } else {
        for (int tt = 0; tt < CS; ++tt) {
            size_t base = (size_t)b * HW + t0 + tt;
            const float4* xd4 = reinterpret_cast<const float4*>(xdbl + base * 36);
            float4 x0 = xd4[0];
            float4 B0 = xd4[1], B1 = xd4[2], B2 = xd4[3], B3 = xd4[4];
            float dt = softplus_f(w.x * x0.x + w.y * x0.y + w.z * x0.z + w.w * x0.w + bb);
            CONV_STEP(base)
            float du = dt * uu;
            sdt += dt;
            UPD4E(h0, a0v, B0) UPD4E(h1, a1v, B1) UPD4E(h2, a2v, B2) UPD4E(h3, a3v, B3)
        }
    }
    size_t o = (size_t)blk * DI + d;
    cDT[o] = sdt;
    float4* cs4 = reinterpret_cast<float4*>(cS + o * NS);
    cs4[0] = h0; cs4[1] = h1; cs4[2] = h2; cs4[3] = h3;
}

// ------ scan pass 2: sequential chunk combine per (b,d,n), IN PLACE on cS ------
__global__ __launch_bounds__(256) void k_scan2(float* __restrict__ cS,
                                               const float* __restrict__ cDT,
                                               const float* __restrict__ Alog) {
    int idx = blockIdx.x * 256 + threadIdx.x;
    if (idx >= Bn * DI * NS) return;
    int n = idx & 15;
    int d = (idx >> 4) & 127;
    int b = idx >> 11;
    float a = -__expf(Alog[d * NS + n]);
    float h = 0.f;
    for (int c = 0; c < NC; ++c) {
        size_t o = (size_t)(b * NC + c) * DI + d;
        float s = cS[o * NS + n];
        cS[o * NS + n] = h;
        h = __expf(a * cDT[o]) * h + s;
    }
}

// ------- scan pass 3: re-scan with proper h0, emit gated y into uy -------------
__global__ __launch_bounds__(128, 4) void k_scan3(float* __restrict__ uy,
                                                  const float* __restrict__ xz,
                                                  const float* __restrict__ xdbl,
                                                  const float* __restrict__ dpw,
                                                  const float* __restrict__ dpb,
                                                  const float* __restrict__ Alog,
                                                  const float* __restrict__ Dp,
                                                  const float* __restrict__ cw,
                                                  const float* __restrict__ cb,
                                                  const float* __restrict__ iS) {
    int blk = blockIdx.x;
    int b = blk / NC;
    int c = blk % NC;
    int d = threadIdx.x;
    float4 a0v, a1v, a2v, a3v;
    float a0;
    bool fast = load_a_struct(Alog, d, a0v, a1v, a2v, a3v, a0);
    float4 w = *reinterpret_cast<const float4*>(dpw + d * 4);
    float bb = dpb[d];
    float Dv = Dp[d];
    float4 cwv = *reinterpret_cast<const float4*>(cw + d * 4);
    float cbv = cb[d];
    size_t so = (size_t)blk * DI + d;
    const float4* is4 = reinterpret_cast<const float4*>(iS + so * NS);
    float4 h0 = is4[0], h1 = is4[1], h2 = is4[2], h3 = is4[3];
    int t0 = c * CS;
    CONV_WARMUP
    if (fast) {
        for (int tt = 0; tt < CS; ++tt) {
            size_t base = (size_t)b * HW + t0 + tt;
            const float4* xd4 = reinterpret_cast<const float4*>(xdbl + base * 36);
            float4 x0 = xd4[0];
            float4 B0 = xd4[1], B1 = xd4[2], B2 = xd4[3], B3 = xd4[4];
            float4 C0 = xd4[5], C1 = xd4[6], C2 = xd4[7], C3 = xd4[8];
            float dt = softplus_f(w.x * x0.x + w.y * x0.y + w.z * x0.z + w.w * x0.w + bb);
            CONV_STEP(base)
            float du = dt * uu;
            float4 D0, D1, D2, D3;
            POWERS(dt, a0, D0, D1, D2, D3)
            UPD4D(h0, D0, B0) UPD4D(h1, D1, B1) UPD4D(h2, D2, B2) UPD4D(h3, D3, B3)
            float y = h0.x * C0.x + h0.y * C0.y + h0.z * C0.z + h0.w * C0.w
                    + h1.x * C1.x + h1.y * C1.y + h1.z * C1.z + h1.w * C1.w
                    + h2.x * C2.x + h2.y * C2.y + h2.z * C2.z + h2.w * C2.w
                    + h3.x * C3.x + h3.y * C3.y + h3.z * C3.z + h3.w * C3.w;
            y += uu * Dv;
            float zz = xz[base * 256 + 128 + d];
            y *= zz * sigmoid_f(zz);
            uy[base * DI + d] = y;
        }
    } else {
        for (int tt = 0; tt < CS; ++tt) {
            size_t base = (size_t)b * HW + t0 + tt;
            const float4* xd4 = reinterpret_cast<const float4*>(xdbl + base * 36);
            float4 x0 = xd4[0];
            float4 B0 = xd4[1], B1 = xd4[2], B2 = xd4[3], B3 = xd4[4];
            float4 C0 = xd4[5], C1 = xd4[6], C2 = xd4[7], C3 = xd4[8];
            float dt = softplus_f(w.x * x0.x + w.y * x0.y + w.z * x0.z + w.w * x0.w + bb);
            CONV_STEP(base)
            float du = dt * uu;
            UPD4E(h0, a0v, B0) UPD4E(h1, a1v, B1) UPD4E(h2, a2v, B2) UPD4E(h3, a3v, B3)
            float y = h0.x * C0.x + h0.y * C0.y + h0.z * C0.z + h0.w * C0.w
                    + h1.x * C1.x + h1.y * C1.y + h1.z * C1.z + h1.w * C1.w
                    + h2.x * C2.x + h2.y * C2.y + h2.z * C2.z + h2.w * C2.w
                    + h3.x * C3.x + h3.y * C3.y + h3.z * C3.z + h3.w * C3.w;
            y += uu * Dv;
            float zz = xz[base * 256 + 128 + d];
            y *= zz * sigmoid_f(zz);
            uy[base * DI + d] = y;
        }
    }
}

// ------- head with fused LN2 + residual: out = z - (LN(feat) @ head_w.T + hb) ---
__global__ __launch_bounds__(256) void k_head(const float* __restrict__ feat,
                                              const float* __restrict__ hwt,
                                              const float* __restrict__ hb,
                                              const float* __restrict__ g,
                                              const float* __restrict__ bta,
                                              const float* __restrict__ z,
                                              float* __restrict__ out) {
    __shared__ float fl[64 * 65];
    int row0 = blockIdx.x * 64;
    for (int i = threadIdx.x; i < 64 * 64; i += 256) {
        int r = i >> 6;
        int m = i & 63;
        fl[r * 65 + m] = feat[(size_t)(row0 + r) * 64 + m];
    }
    __syncthreads();
    int r = threadIdx.x >> 2;
    int c = threadIdx.x & 3;
    int m0 = c * 16;
    float s = 0.f;
#pragma unroll
    for (int mi = 0; mi < 16; ++mi) s += fl[r * 65 + m0 + mi];
    s += __shfl_xor(s, 1, 64);
    s += __shfl_xor(s, 2, 64);
    float mu = s * (1.f / 64.f);
    float v = 0.f;
#pragma unroll
    for (int mi = 0; mi < 16; ++mi) {
        float dd = fl[r * 65 + m0 + mi] - mu;
        v += dd * dd;
    }
    v += __shfl_xor(v, 1, 64);
    v += __shfl_xor(v, 2, 64);
    float rs = rsqrtf(v * (1.f / 64.f) + 1e-5f);
#pragma unroll
    for (int mi = 0; mi < 16; ++mi) {
        int m = m0 + mi;
        float x = fl[r * 65 + m];
        fl[r * 65 + m] = (x - mu) * rs * g[m] + bta[m];
    }
    __syncthreads();
    float acc = hb[c];
#pragma unroll
    for (int m = 0; m < 64; ++m) acc += fl[r * 65 + m] * hwt[c * 64 + m];
    int bl = row0 + r;
    int b = bl >> 12;
    int hw = bl & 4095;
    size_t o = ((size_t)b * 4 + c) * HW + hw;
    out[o] = z[o] - acc;
}

// -------------------------------------------------------------------------------
static void run_mamba(const float* const* P, float* feat, float* xz, float* u,
                      float* xdbl, float* cS, float* cDT, hipStream_t s) {
    // P: 0 in_proj_w, 1 conv_w, 2 conv_b, 3 x_proj_w, 4 dt_proj_w, 5 dt_proj_b,
    //    6 A_log, 7 D, 8 out_proj_w
    k_gemm<64, 64><<<dim3(BL / 64, 4), 256, 0, s>>>(feat, P[0], xz, 256);
    k_xproj<<<BL / 64, 256, 0, s>>>(xz, P[3], P[1], P[2], xdbl);
    k_scan1<<<Bn * NC, DI, 0, s>>>(xz, xdbl, P[4], P[5], P[6], P[1], P[2], cS, cDT);
    k_scan2<<<(Bn * DI * NS) / 256, 256, 0, s>>>(cS, cDT, P[6]);
    k_scan3<<<Bn * NC, DI, 0, s>>>(u, xz, xdbl, P[4], P[5], P[6], P[7], P[1], P[2], cS);
    k_gemm<128, 64><<<dim3(BL / 64, 1), 256, 0, s>>>(u, P[8], feat, 64);
}

extern "C" void kernel_launch(void* const* d_in, const int* in_sizes, int n_in,
                              void* d_out, int out_size, void* d_ws, size_t ws_size,
                              hipStream_t stream) {
    const float* z = (const float*)d_in[0];
    const float* ew = (const float*)d_in[1];
    const float* eb = (const float*)d_in[2];
    const float* m1[9];
    const float* m2[9];
    for (int i = 0; i < 9; ++i) m1[i] = (const float*)d_in[3 + i];
    for (int i = 0; i < 9; ++i) m2[i] = (const float*)d_in[12 + i];
    const float* ln1g = (const float*)d_in[21];
    const float* ln1b = (const float*)d_in[22];
    const float* ln2g = (const float*)d_in[23];
    const float* ln2b = (const float*)d_in[24];
    const float* hwt = (const float*)d_in[25];
    const float* hb = (const float*)d_in[26];

    float* ws = (float*)d_ws;
    float* feat = ws;                         // BL*64
    float* xz = feat + (size_t)BL * 64;       // BL*256
    float* u = xz + (size_t)BL * 256;         // BL*128
    float* xdbl = u + (size_t)BL * 128;       // BL*36
    float* cS = xdbl + (size_t)BL * 36;       // Bn*NC*DI*NS
    float* cDT = cS + (size_t)Bn * NC * DI * NS;  // Bn*NC*DI

    k_embed<<<(BL * DM) / 256, 256, 0, stream>>>(z, ew, eb, feat);
    run_mamba(m1, feat, xz, u, xdbl, cS, cDT, stream);
    k_ln<<<4096, 256, 0, stream>>>(feat, ln1g, ln1b, BL);
    run_mamba(m2, feat, xz, u, xdbl, cS, cDT, stream);
    // LN2 is fused inside k_head — no standalone k_ln here (round-14 bug: double LN).
    k_head<<<BL / 64, 256, 0, stream>>>(feat, hwt, hb, ln2g, ln2b, z, (float*)d_out);
}

// Round 16
// 496.940 us; speedup vs baseline: 1.1236x; 1.1236x over previous
//
#include <hip/hip_runtime.h>
#include <hip/hip_bf16.h>

#define DEV __device__ __forceinline__

static constexpr int Bn = 16;
static constexpr int Cc = 4;
static constexpr int HW = 4096;      // L (=64*64)
static constexpr int BL = Bn * HW;   // 65536 rows
static constexpr int DM = 64;
static constexpr int DI = 128;
static constexpr int NS = 16;        // D_STATE
static constexpr int NC = 256;       // chunks per sequence
static constexpr int CS = HW / NC;   // 16 steps per chunk

DEV float sigmoid_f(float x) { return 1.f / (1.f + __expf(-x)); }
DEV float softplus_f(float x) {
    return fmaxf(x, 0.f) + __logf(1.f + __expf(-fabsf(x)));
}
DEV float silu_f(float x) { return x / (1.f + __expf(-x)); }

// ---------------- embed: feat[b,l,m] = sum_c z[b,c,l]*ew[m,c] + eb[m] ----------
__global__ __launch_bounds__(256) void k_embed(const float* __restrict__ z,
                                               const float* __restrict__ ew,
                                               const float* __restrict__ eb,
                                               float* __restrict__ feat) {
    int idx = blockIdx.x * 256 + threadIdx.x;          // over BL*DM
    if (idx >= BL * DM) return;
    int m = idx & 63;
    int bl = idx >> 6;
    int b = bl >> 12;
    int hw = bl & 4095;
    const float* zp = z + (size_t)b * Cc * HW + hw;
    float acc = eb[m];
#pragma unroll
    for (int c = 0; c < 4; ++c) acc += zp[(size_t)c * HW] * ew[m * 4 + c];
    feat[idx] = acc;
}

// ---------------- layernorm over last dim (64), in place -----------------------
__global__ __launch_bounds__(256) void k_ln(float* __restrict__ feat,
                                            const float* __restrict__ g,
                                            const float* __restrict__ bta, int R) {
    int lane = threadIdx.x & 63;
    int wv = blockIdx.x * 4 + (threadIdx.x >> 6);
    int stride = gridDim.x * 4;
    for (int row = wv; row < R; row += stride) {
        float x = feat[(size_t)row * 64 + lane];
        float s = x;
#pragma unroll
        for (int off = 32; off; off >>= 1) s += __shfl_xor(s, off, 64);
        float mu = s * (1.f / 64.f);
        float xm = x - mu;
        float v = xm * xm;
#pragma unroll
        for (int off = 32; off; off >>= 1) v += __shfl_xor(v, off, 64);
        float var = v * (1.f / 64.f);
        feat[(size_t)row * 64 + lane] = xm * rsqrtf(var + 1e-5f) * g[lane] + bta[lane];
    }
}

// ---- register-tiled GEMM: out[r, n0+c] = sum_k in[r,k] * W[n0+c, k] -----------
// TM=4/TN=4, 256 compute threads, interleaved rows (r = ty + i*16), k4-major
// conflict-free Ws staging. k-loop unroll capped at 4: full unroll (r15) kept
// ~8 float4 LDS results live -> 144 VGPR -> 10% occupancy, latency-bound.
template <int K, int BN>
__global__ __launch_bounds__(256) void k_gemm(const float* __restrict__ in,
                                              const float* __restrict__ W,
                                              float* __restrict__ out,
                                              int Nfull) {
    constexpr int BM = 64, TM = 4, TN = 4;
    constexpr int CT = BN / TN;        // 16
    constexpr int RT = BM / TM;        // 16
    constexpr int KP = K + 4;
    constexpr int WP = BN + 4;
    __shared__ float As[BM * KP];
    __shared__ float Ws[K * WP];
    int tid = threadIdx.x;
    int n0 = blockIdx.y * BN;
    int row0 = blockIdx.x * BM;
    // stage W transposed, k4-major (lanes span c -> all banks, conflict-free)
    for (int i = tid; i < BN * (K / 4); i += 256) {
        int k4 = i / BN;
        int c = i - k4 * BN;
        float4 w = *reinterpret_cast<const float4*>(&W[(size_t)(n0 + c) * K + k4 * 4]);
        Ws[(k4 * 4 + 0) * WP + c] = w.x;
        Ws[(k4 * 4 + 1) * WP + c] = w.y;
        Ws[(k4 * 4 + 2) * WP + c] = w.z;
        Ws[(k4 * 4 + 3) * WP + c] = w.w;
    }
    // stage A tile
    for (int i = tid; i < BM * (K / 4); i += 256) {
        int r = i / (K / 4);
        int k4 = i - r * (K / 4);
        *reinterpret_cast<float4*>(&As[r * KP + k4 * 4]) =
            *reinterpret_cast<const float4*>(&in[(size_t)(row0 + r) * K + k4 * 4]);
    }
    __syncthreads();
    // GEMM: thread (ty,tx) owns rows {ty + i*RT} x cols {tx*4..+3}
    int ty = tid / CT, tx = tid - (tid / CT) * CT;
    int c0 = tx * TN;
    float acc[TM][TN];
#pragma unroll
    for (int i = 0; i < TM; ++i)
#pragma unroll
        for (int c = 0; c < TN; ++c) acc[i][c] = 0.f;
#pragma unroll 4
    for (int k = 0; k < K; k += 4) {
        float4 a[TM];
#pragma unroll
        for (int i = 0; i < TM; ++i)
            a[i] = *reinterpret_cast<const float4*>(&As[(ty + i * RT) * KP + k]);
        float4 b0 = *reinterpret_cast<const float4*>(&Ws[(k + 0) * WP + c0]);
        float4 b1 = *reinterpret_cast<const float4*>(&Ws[(k + 1) * WP + c0]);
        float4 b2 = *reinterpret_cast<const float4*>(&Ws[(k + 2) * WP + c0]);
        float4 b3 = *reinterpret_cast<const float4*>(&Ws[(k + 3) * WP + c0]);
#pragma unroll
        for (int i = 0; i < TM; ++i) {
            acc[i][0] += a[i].x * b0.x + a[i].y * b1.x + a[i].z * b2.x + a[i].w * b3.x;
            acc[i][1] += a[i].x * b0.y + a[i].y * b1.y + a[i].z * b2.y + a[i].w * b3.y;
            acc[i][2] += a[i].x * b0.z + a[i].y * b1.z + a[i].z * b2.z + a[i].w * b3.z;
            acc[i][3] += a[i].x * b0.w + a[i].y * b1.w + a[i].z * b2.w + a[i].w * b3.w;
        }
    }
#pragma unroll
    for (int i = 0; i < TM; ++i) {
        size_t o = (size_t)(row0 + ty + i * RT) * Nfull + n0 + c0;
        float4 v = {acc[i][0], acc[i][1], acc[i][2], acc[i][3]};
        *reinterpret_cast<float4*>(&out[o]) = v;
    }
}

// ---- x_proj with fused causal conv+SiLU ---------------------------------------
__global__ __launch_bounds__(256) void k_xproj(const float* __restrict__ xz,
                                               const float* __restrict__ W,
                                               const float* __restrict__ cw,
                                               const float* __restrict__ cb,
                                               float* __restrict__ xdbl) {
    constexpr int BM = 64, K = 128, BN = 36, TN = 3, TM = 4;
    constexpr int CT = BN / TN;   // 12
    constexpr int RT = BM / TM;   // 16
    constexpr int KP = K + 4;     // 132
    constexpr int WP = BN + 4;    // 40
    __shared__ float Xs[(BM + 3) * KP];
    __shared__ float Ws[K * WP];
    int tid = threadIdx.x;
    int row0 = blockIdx.x * BM;
    bool first = (row0 & 4095) == 0;
    for (int i = tid; i < BN * (K / 4); i += 256) {
        int k4 = i / BN;
        int c = i - k4 * BN;
        float4 w = *reinterpret_cast<const float4*>(&W[(size_t)c * K + k4 * 4]);
        Ws[(k4 * 4 + 0) * WP + c] = w.x;
        Ws[(k4 * 4 + 1) * WP + c] = w.y;
        Ws[(k4 * 4 + 2) * WP + c] = w.z;
        Ws[(k4 * 4 + 3) * WP + c] = w.w;
    }
    for (int i = tid; i < (BM + 3) * (K / 4); i += 256) {
        int r = i / (K / 4);
        int k4 = i - r * (K / 4);
        float4 v = {0, 0, 0, 0};
        if (!first || r >= 3)
            v = *reinterpret_cast<const float4*>(&xz[(size_t)(row0 - 3 + r) * 256 + k4 * 4]);
        *reinterpret_cast<float4*>(&Xs[r * KP + k4 * 4]) = v;
    }
    __syncthreads();
    {
        int rg = tid >> 5;
        int c0 = (tid & 31) * 4;
        float4 wr[4];
#pragma unroll
        for (int j = 0; j < 4; ++j)
            wr[j] = *reinterpret_cast<const float4*>(&cw[(c0 + j) * 4]);
        float4 cb4 = *reinterpret_cast<const float4*>(&cb[c0]);
        int R0 = rg * 8;
        float4 xr[11];
#pragma unroll
        for (int j = 0; j < 11; ++j)
            xr[j] = *reinterpret_cast<const float4*>(&Xs[(R0 + j) * KP + c0]);
        float4 ur[8];
#pragma unroll
        for (int j = 0; j < 8; ++j) {
            float4 acc;
            acc.x = cb4.x + wr[0].x * xr[j].x + wr[0].y * xr[j + 1].x + wr[0].z * xr[j + 2].x + wr[0].w * xr[j + 3].x;
            acc.y = cb4.y + wr[1].x * xr[j].y + wr[1].y * xr[j + 1].y + wr[1].z * xr[j + 2].y + wr[1].w * xr[j + 3].y;
            acc.z = cb4.z + wr[2].x * xr[j].z + wr[2].y * xr[j + 1].z + wr[2].z * xr[j + 2].z + wr[2].w * xr[j + 3].z;
            acc.w = cb4.w + wr[3].x * xr[j].w + wr[3].y * xr[j + 1].w + wr[3].z * xr[j + 2].w + wr[3].w * xr[j + 3].w;
            ur[j].x = silu_f(acc.x);
            ur[j].y = silu_f(acc.y);
            ur[j].z = silu_f(acc.z);
            ur[j].w = silu_f(acc.w);
        }
        __syncthreads();
#pragma unroll
        for (int j = 0; j < 8; ++j)
            *reinterpret_cast<float4*>(&Xs[(R0 + j) * KP + c0]) = ur[j];
    }
    __syncthreads();
    if (tid < CT * RT) {
        int ty = tid / CT, tx = tid - (tid / CT) * CT;
        int c0 = tx * TN;
        float acc[TM][TN];
#pragma unroll
        for (int i = 0; i < TM; ++i)
#pragma unroll
            for (int c = 0; c < TN; ++c) acc[i][c] = 0.f;
#pragma unroll 4
        for (int k = 0; k < K; k += 4) {
            float4 a[TM];
#pragma unroll
            for (int i = 0; i < TM; ++i)
                a[i] = *reinterpret_cast<const float4*>(&Xs[(ty + i * RT) * KP + k]);
            float bv[4][TN];
#pragma unroll
            for (int j = 0; j < 4; ++j)
#pragma unroll
                for (int c = 0; c < TN; ++c) bv[j][c] = Ws[(k + j) * WP + c0 + c];
#pragma unroll
            for (int i = 0; i < TM; ++i)
#pragma unroll
                for (int c = 0; c < TN; ++c)
                    acc[i][c] += a[i].x * bv[0][c] + a[i].y * bv[1][c]
                               + a[i].z * bv[2][c] + a[i].w * bv[3][c];
        }
#pragma unroll
        for (int i = 0; i < TM; ++i) {
            size_t o = (size_t)(row0 + ty + i * RT) * BN + c0;
#pragma unroll
            for (int c = 0; c < TN; ++c) xdbl[o + c] = acc[i][c];
        }
    }
}

// ---- helpers for the scan kernels --------------------------------------------
DEV bool load_a_struct(const float* Alog, int d, float4& a0v, float4& a1v,
                       float4& a2v, float4& a3v, float& a0) {
    const float4* al = reinterpret_cast<const float4*>(Alog + d * NS);
    float4 t0 = al[0], t1 = al[1], t2 = al[2], t3 = al[3];
    a0v.x = -__expf(t0.x); a0v.y = -__expf(t0.y); a0v.z = -__expf(t0.z); a0v.w = -__expf(t0.w);
    a1v.x = -__expf(t1.x); a1v.y = -__expf(t1.y); a1v.z = -__expf(t1.z); a1v.w = -__expf(t1.w);
    a2v.x = -__expf(t2.x); a2v.y = -__expf(t2.y); a2v.z = -__expf(t2.z); a2v.w = -__expf(t2.w);
    a3v.x = -__expf(t3.x); a3v.y = -__expf(t3.y); a3v.z = -__expf(t3.z); a3v.w = -__expf(t3.w);
    a0 = a0v.x;
    float aa[16] = {a0v.x, a0v.y, a0v.z, a0v.w, a1v.x, a1v.y, a1v.z, a1v.w,
                    a2v.x, a2v.y, a2v.z, a2v.w, a3v.x, a3v.y, a3v.z, a3v.w};
    bool fast = true;
#pragma unroll
    for (int n = 0; n < 16; ++n)
        fast = fast && (fabsf(aa[n] - a0 * (float)(n + 1)) <= 1e-4f * (float)(n + 1));
    return fast;
}

#define POWERS(dt, a0, D0, D1, D2, D3)                        \
    {                                                         \
        float E1 = __expf((dt) * (a0));                       \
        float E2 = E1 * E1, E3 = E2 * E1, E4 = E2 * E2;       \
        float E5 = E3 * E2, E6 = E3 * E3, E7 = E4 * E3;       \
        float E8 = E4 * E4, E9 = E5 * E4, E10 = E5 * E5;      \
        float E11 = E6 * E5, E12 = E6 * E6, E13 = E7 * E6;    \
        float E14 = E7 * E7, E15 = E8 * E7, E16 = E8 * E8;    \
        D0 = {E1, E2, E3, E4};                                \
        D1 = {E5, E6, E7, E8};                                \
        D2 = {E9, E10, E11, E12};                             \
        D3 = {E13, E14, E15, E16};                            \
    }

#define UPD4D(H, DA, BV)                          \
    H.x = DA.x * H.x + du * BV.x;                 \
    H.y = DA.y * H.y + du * BV.y;                 \
    H.z = DA.z * H.z + du * BV.z;                 \
    H.w = DA.w * H.w + du * BV.w;

#define UPD4E(H, A, BV)                                  \
    H.x = __expf(dt * A.x) * H.x + du * BV.x;            \
    H.y = __expf(dt * A.y) * H.y + du * BV.y;            \
    H.z = __expf(dt * A.z) * H.z + du * BV.z;            \
    H.w = __expf(dt * A.w) * H.w + du * BV.w;

#define CONV_WARMUP                                                     \
    float x3 = 0.f, x2 = 0.f, x1 = 0.f;                                 \
    if (c != 0) {                                                       \
        size_t wb = ((size_t)b * HW + t0) * 256 + d;                    \
        x3 = xz[wb - 3 * 256];                                          \
        x2 = xz[wb - 2 * 256];                                          \
        x1 = xz[wb - 1 * 256];                                          \
    }

#define CONV_STEP(base)                                                 \
    float xv = xz[(base) * 256 + d];                                    \
    float cacc = cbv + cwv.x * x3 + cwv.y * x2 + cwv.z * x1 + cwv.w * xv; \
    float uu = cacc * sigmoid_f(cacc);                                  \
    x3 = x2; x2 = x1; x1 = xv;

// ---------------- scan pass 1: per-chunk local scan (h0 = 0) -------------------
__global__ __launch_bounds__(128, 4) void k_scan1(const float* __restrict__ xz,
                                                  const float* __restrict__ xdbl,
                                                  const float* __restrict__ dpw,
                                                  const float* __restrict__ dpb,
                                                  const float* __restrict__ Alog,
                                                  const float* __restrict__ cw,
                                                  const float* __restrict__ cb,
                                                  float* __restrict__ cS,
                                                  float* __restrict__ cDT) {
    int blk = blockIdx.x;
    int b = blk / NC;
    int c = blk % NC;
    int d = threadIdx.x;
    float4 a0v, a1v, a2v, a3v;
    float a0;
    bool fast = load_a_struct(Alog, d, a0v, a1v, a2v, a3v, a0);
    float4 w = *reinterpret_cast<const float4*>(dpw + d * 4);
    float bb = dpb[d];
    float4 cwv = *reinterpret_cast<const float4*>(cw + d * 4);
    float cbv = cb[d];
    float4 h0 = {0, 0, 0, 0}, h1 = {0, 0, 0, 0}, h2 = {0, 0, 0, 0}, h3 = {0, 0, 0, 0};
    float sdt = 0.f;
    int t0 = c * CS;
    CONV_WARMUP
    if (fast) {
        for (int tt = 0; tt < CS; ++tt) {
            size_t base = (size_t)b * HW + t0 + tt;
            const float4* xd4 = reinterpret_cast<const float4*>(xdbl + base * 36);
            float4 x0 = xd4[0];
            float4 B0 = xd4[1], B1 = xd4[2], B2 = xd4[3], B3 = xd4[4];
            float dt = softplus_f(w.x * x0.x + w.y * x0.y + w.z * x0.z + w.w * x0.w + bb);
            CONV_STEP(base)
            float du = dt * uu;
            sdt += dt;
            float4 D0, D1, D2, D3;
            POWERS(dt, a0, D0, D1, D2, D3)
            UPD4D(h0, D0, B0) UPD4D(h1, D1, B1) UPD4D(h2, D2, B2) UPD4D(h3, D3, B3)
        }
    } else {
        for (int tt = 0; tt < CS; ++tt) {
            size_t base = (size_t)b * HW + t0 + tt;
            const float4* xd4 = reinterpret_cast<const float4*>(xdbl + base * 36);
            float4 x0 = xd4[0];
            float4 B0 = xd4[1], B1 = xd4[2], B2 = xd4[3], B3 = xd4[4];
            float dt = softplus_f(w.x * x0.x + w.y * x0.y + w.z * x0.z + w.w * x0.w + bb);
            CONV_STEP(base)
            float du = dt * uu;
            sdt += dt;
            UPD4E(h0, a0v, B0) UPD4E(h1, a1v, B1) UPD4E(h2, a2v, B2) UPD4E(h3, a3v, B3)
        }
    }
    size_t o = (size_t)blk * DI + d;
    cDT[o] = sdt;
    float4* cs4 = reinterpret_cast<float4*>(cS + o * NS);
    cs4[0] = h0; cs4[1] = h1; cs4[2] = h2; cs4[3] = h3;
}

// ------ scan pass 2: sequential chunk combine per (b,d,n), IN PLACE on cS ------
__global__ __launch_bounds__(256) void k_scan2(float* __restrict__ cS,
                                               const float* __restrict__ cDT,
                                               const float* __restrict__ Alog) {
    int idx = blockIdx.x * 256 + threadIdx.x;
    if (idx >= Bn * DI * NS) return;
    int n = idx & 15;
    int d = (idx >> 4) & 127;
    int b = idx >> 11;
    float a = -__expf(Alog[d * NS + n]);
    float h = 0.f;
    for (int c = 0; c < NC; ++c) {
        size_t o = (size_t)(b * NC + c) * DI + d;
        float s = cS[o * NS + n];
        cS[o * NS + n] = h;
        h = __expf(a * cDT[o]) * h + s;
    }
}

// ------- scan pass 3: re-scan with proper h0, emit gated y into uy -------------
__global__ __launch_bounds__(128, 4) void k_scan3(float* __restrict__ uy,
                                                  const float* __restrict__ xz,
                                                  const float* __restrict__ xdbl,
                                                  const float* __restrict__ dpw,
                                                  const float* __restrict__ dpb,
                                                  const float* __restrict__ Alog,
                                                  const float* __restrict__ Dp,
                                                  const float* __restrict__ cw,
                                                  const float* __restrict__ cb,
                                                  const float* __restrict__ iS) {
    int blk = blockIdx.x;
    int b = blk / NC;
    int c = blk % NC;
    int d = threadIdx.x;
    float4 a0v, a1v, a2v, a3v;
    float a0;
    bool fast = load_a_struct(Alog, d, a0v, a1v, a2v, a3v, a0);
    float4 w = *reinterpret_cast<const float4*>(dpw + d * 4);
    float bb = dpb[d];
    float Dv = Dp[d];
    float4 cwv = *reinterpret_cast<const float4*>(cw + d * 4);
    float cbv = cb[d];
    size_t so = (size_t)blk * DI + d;
    const float4* is4 = reinterpret_cast<const float4*>(iS + so * NS);
    float4 h0 = is4[0], h1 = is4[1], h2 = is4[2], h3 = is4[3];
    int t0 = c * CS;
    CONV_WARMUP
    if (fast) {
        for (int tt = 0; tt < CS; ++tt) {
            size_t base = (size_t)b * HW + t0 + tt;
            const float4* xd4 = reinterpret_cast<const float4*>(xdbl + base * 36);
            float4 x0 = xd4[0];
            float4 B0 = xd4[1], B1 = xd4[2], B2 = xd4[3], B3 = xd4[4];
            float4 C0 = xd4[5], C1 = xd4[6], C2 = xd4[7], C3 = xd4[8];
            float dt = softplus_f(w.x * x0.x + w.y * x0.y + w.z * x0.z + w.w * x0.w + bb);
            CONV_STEP(base)
            float du = dt * uu;
            float4 D0, D1, D2, D3;
            POWERS(dt, a0, D0, D1, D2, D3)
            UPD4D(h0, D0, B0) UPD4D(h1, D1, B1) UPD4D(h2, D2, B2) UPD4D(h3, D3, B3)
            float y = h0.x * C0.x + h0.y * C0.y + h0.z * C0.z + h0.w * C0.w
                    + h1.x * C1.x + h1.y * C1.y + h1.z * C1.z + h1.w * C1.w
                    + h2.x * C2.x + h2.y * C2.y + h2.z * C2.z + h2.w * C2.w
                    + h3.x * C3.x + h3.y * C3.y + h3.z * C3.z + h3.w * C3.w;
            y += uu * Dv;
            float zz = xz[base * 256 + 128 + d];
            y *= zz * sigmoid_f(zz);
            uy[base * DI + d] = y;
        }
    } else {
        for (int tt = 0; tt < CS; ++tt) {
            size_t base = (size_t)b * HW + t0 + tt;
            const float4* xd4 = reinterpret_cast<const float4*>(xdbl + base * 36);
            float4 x0 = xd4[0];
            float4 B0 = xd4[1], B1 = xd4[2], B2 = xd4[3], B3 = xd4[4];
            float4 C0 = xd4[5], C1 = xd4[6], C2 = xd4[7], C3 = xd4[8];
            float dt = softplus_f(w.x * x0.x + w.y * x0.y + w.z * x0.z + w.w * x0.w + bb);
            CONV_STEP(base)
            float du = dt * uu;
            UPD4E(h0, a0v, B0) UPD4E(h1, a1v, B1) UPD4E(h2, a2v, B2) UPD4E(h3, a3v, B3)
            float y = h0.x * C0.x + h0.y * C0.y + h0.z * C0.z + h0.w * C0.w
                    + h1.x * C1.x + h1.y * C1.y + h1.z * C1.z + h1.w * C1.w
                    + h2.x * C2.x + h2.y * C2.y + h2.z * C2.z + h2.w * C2.w
                    + h3.x * C3.x + h3.y * C3.y + h3.z * C3.z + h3.w * C3.w;
            y += uu * Dv;
            float zz = xz[base * 256 + 128 + d];
            y *= zz * sigmoid_f(zz);
            uy[base * DI + d] = y;
        }
    }
}

// ------- head with fused LN2 + residual: out = z - (LN(feat) @ head_w.T + hb) ---
__global__ __launch_bounds__(256) void k_head(const float* __restrict__ feat,
                                              const float* __restrict__ hwt,
                                              const float* __restrict__ hb,
                                              const float* __restrict__ g,
                                              const float* __restrict__ bta,
                                              const float* __restrict__ z,
                                              float* __restrict__ out) {
    __shared__ float fl[64 * 65];
    int row0 = blockIdx.x * 64;
    for (int i = threadIdx.x; i < 64 * 64; i += 256) {
        int r = i >> 6;
        int m = i & 63;
        fl[r * 65 + m] = feat[(size_t)(row0 + r) * 64 + m];
    }
    __syncthreads();
    int r = threadIdx.x >> 2;
    int c = threadIdx.x & 3;
    int m0 = c * 16;
    float s = 0.f;
#pragma unroll
    for (int mi = 0; mi < 16; ++mi) s += fl[r * 65 + m0 + mi];
    s += __shfl_xor(s, 1, 64);
    s += __shfl_xor(s, 2, 64);
    float mu = s * (1.f / 64.f);
    float v = 0.f;
#pragma unroll
    for (int mi = 0; mi < 16; ++mi) {
        float dd = fl[r * 65 + m0 + mi] - mu;
        v += dd * dd;
    }
    v += __shfl_xor(v, 1, 64);
    v += __shfl_xor(v, 2, 64);
    float rs = rsqrtf(v * (1.f / 64.f) + 1e-5f);
#pragma unroll
    for (int mi = 0; mi < 16; ++mi) {
        int m = m0 + mi;
        float x = fl[r * 65 + m];
        fl[r * 65 + m] = (x - mu) * rs * g[m] + bta[m];
    }
    __syncthreads();
    float acc = hb[c];
#pragma unroll
    for (int m = 0; m < 64; ++m) acc += fl[r * 65 + m] * hwt[c * 64 + m];
    int bl = row0 + r;
    int b = bl >> 12;
    int hw = bl & 4095;
    size_t o = ((size_t)b * 4 + c) * HW + hw;
    out[o] = z[o] - acc;
}

// -------------------------------------------------------------------------------
static void run_mamba(const float* const* P, float* feat, float* xz, float* u,
                      float* xdbl, float* cS, float* cDT, hipStream_t s) {
    // P: 0 in_proj_w, 1 conv_w, 2 conv_b, 3 x_proj_w, 4 dt_proj_w, 5 dt_proj_b,
    //    6 A_log, 7 D, 8 out_proj_w
    k_gemm<64, 64><<<dim3(BL / 64, 4), 256, 0, s>>>(feat, P[0], xz, 256);
    k_xproj<<<BL / 64, 256, 0, s>>>(xz, P[3], P[1], P[2], xdbl);
    k_scan1<<<Bn * NC, DI, 0, s>>>(xz, xdbl, P[4], P[5], P[6], P[1], P[2], cS, cDT);
    k_scan2<<<(Bn * DI * NS) / 256, 256, 0, s>>>(cS, cDT, P[6]);
    k_scan3<<<Bn * NC, DI, 0, s>>>(u, xz, xdbl, P[4], P[5], P[6], P[7], P[1], P[2], cS);
    k_gemm<128, 64><<<dim3(BL / 64, 1), 256, 0, s>>>(u, P[8], feat, 64);
}

extern "C" void kernel_launch(void* const* d_in, const int* in_sizes, int n_in,
                              void* d_out, int out_size, void* d_ws, size_t ws_size,
                              hipStream_t stream) {
    const float* z = (const float*)d_in[0];
    const float* ew = (const float*)d_in[1];
    const float* eb = (const float*)d_in[2];
    const float* m1[9];
    const float* m2[9];
    for (int i = 0; i < 9; ++i) m1[i] = (const float*)d_in[3 + i];
    for (int i = 0; i < 9; ++i) m2[i] = (const float*)d_in[12 + i];
    const float* ln1g = (const float*)d_in[21];
    const float* ln1b = (const float*)d_in[22];
    const float* ln2g = (const float*)d_in[23];
    const float* ln2b = (const float*)d_in[24];
    const float* hwt = (const float*)d_in[25];
    const float* hb = (const float*)d_in[26];

    float* ws = (float*)d_ws;
    float* feat = ws;                         // BL*64
    float* xz = feat + (size_t)BL * 64;       // BL*256
    float* u = xz + (size_t)BL * 256;         // BL*128
    float* xdbl = u + (size_t)BL * 128;       // BL*36
    float* cS = xdbl + (size_t)BL * 36;       // Bn*NC*DI*NS
    float* cDT = cS + (size_t)Bn * NC * DI * NS;  // Bn*NC*DI

    k_embed<<<(BL * DM) / 256, 256, 0, stream>>>(z, ew, eb, feat);
    run_mamba(m1, feat, xz, u, xdbl, cS, cDT, stream);
    k_ln<<<4096, 256, 0, stream>>>(feat, ln1g, ln1b, BL);
    run_mamba(m2, feat, xz, u, xdbl, cS, cDT, stream);
    // LN2 is fused inside k_head — no standalone k_ln here (round-14 bug: double LN).
    k_head<<<BL / 64, 256, 0, stream>>>(feat, hwt, hb, ln2g, ln2b, z, (float*)d_out);
}

// Round 17
// 441.003 us; speedup vs baseline: 1.2661x; 1.1268x over previous
//
#include <hip/hip_runtime.h>
#include <hip/hip_bf16.h>

#define DEV __device__ __forceinline__

static constexpr int Bn = 16;
static constexpr int Cc = 4;
static constexpr int HW = 4096;      // L (=64*64)
static constexpr int BL = Bn * HW;   // 65536 rows
static constexpr int DM = 64;
static constexpr int DI = 128;
static constexpr int NS = 16;        // D_STATE
static constexpr int NC = 256;       // chunks per sequence
static constexpr int CS = HW / NC;   // 16 steps per chunk

DEV float sigmoid_f(float x) { return 1.f / (1.f + __expf(-x)); }
DEV float softplus_f(float x) {
    return fmaxf(x, 0.f) + __logf(1.f + __expf(-fabsf(x)));
}
DEV float silu_f(float x) { return x / (1.f + __expf(-x)); }

typedef short bf16x8 __attribute__((ext_vector_type(8)));
typedef float f32x4 __attribute__((ext_vector_type(4)));

// f32 -> bf16 bits, round-to-nearest-even
DEV short f2b(float x) {
    unsigned u = __float_as_uint(x);
    unsigned r = (u + 0x7FFFu + ((u >> 16) & 1u)) >> 16;
    return (short)r;
}

// ---------------- embed: feat[b,l,m] = sum_c z[b,c,l]*ew[m,c] + eb[m] ----------
__global__ __launch_bounds__(256) void k_embed(const float* __restrict__ z,
                                               const float* __restrict__ ew,
                                               const float* __restrict__ eb,
                                               float* __restrict__ feat) {
    int idx = blockIdx.x * 256 + threadIdx.x;          // over BL*DM
    if (idx >= BL * DM) return;
    int m = idx & 63;
    int bl = idx >> 6;
    int b = bl >> 12;
    int hw = bl & 4095;
    const float* zp = z + (size_t)b * Cc * HW + hw;
    float acc = eb[m];
#pragma unroll
    for (int c = 0; c < 4; ++c) acc += zp[(size_t)c * HW] * ew[m * 4 + c];
    feat[idx] = acc;
}

// ---------------- layernorm over last dim (64), in place -----------------------
__global__ __launch_bounds__(256) void k_ln(float* __restrict__ feat,
                                            const float* __restrict__ g,
                                            const float* __restrict__ bta, int R) {
    int lane = threadIdx.x & 63;
    int wv = blockIdx.x * 4 + (threadIdx.x >> 6);
    int stride = gridDim.x * 4;
    for (int row = wv; row < R; row += stride) {
        float x = feat[(size_t)row * 64 + lane];
        float s = x;
#pragma unroll
        for (int off = 32; off; off >>= 1) s += __shfl_xor(s, off, 64);
        float mu = s * (1.f / 64.f);
        float xm = x - mu;
        float v = xm * xm;
#pragma unroll
        for (int off = 32; off; off >>= 1) v += __shfl_xor(v, off, 64);
        float var = v * (1.f / 64.f);
        feat[(size_t)row * 64 + lane] = xm * rsqrtf(var + 1e-5f) * g[lane] + bta[lane];
    }
}

// ---- MFMA GEMM (bf16 in, f32 acc): out[r, c] = sum_k in[r,k] * W[c, k] --------
// Block: 256 threads (4 waves), 64 rows x NTOT cols. W + A tiles staged as bf16
// in LDS (row stride K+8 -> 16B-aligned b128 frags, uniform bank spread).
// Fragments (v_mfma_f32_16x16x32_bf16): A/B lane: row/col = lane&15,
// k = (lane>>4)*8 + j (8 contiguous). C/D: col = lane&15, row = (lane>>4)*4+j.
template <int K, int NTOT>
__global__ __launch_bounds__(256) void k_gemm_mfma(const float* __restrict__ in,
                                                   const float* __restrict__ W,
                                                   float* __restrict__ out) {
    constexpr int KP = K + 8;          // bf16 elems per row (bytes % 16 == 0)
    __shared__ short Wl[NTOT * KP];
    __shared__ short Al[64 * KP];
    int tid = threadIdx.x;
    int row0 = blockIdx.x * 64;
    // stage W (NTOT x K) f32 -> bf16
    for (int i = tid; i < NTOT * (K / 4); i += 256) {
        int r = i / (K / 4);
        int k4 = (i - r * (K / 4)) * 4;
        float4 w = *reinterpret_cast<const float4*>(&W[(size_t)r * K + k4]);
        short4 s = {f2b(w.x), f2b(w.y), f2b(w.z), f2b(w.w)};
        *reinterpret_cast<short4*>(&Wl[r * KP + k4]) = s;
    }
    // stage A (64 x K) f32 -> bf16
    for (int i = tid; i < 64 * (K / 4); i += 256) {
        int r = i / (K / 4);
        int k4 = (i - r * (K / 4)) * 4;
        float4 a = *reinterpret_cast<const float4*>(&in[(size_t)(row0 + r) * K + k4]);
        short4 s = {f2b(a.x), f2b(a.y), f2b(a.z), f2b(a.w)};
        *reinterpret_cast<short4*>(&Al[r * KP + k4]) = s;
    }
    __syncthreads();
    int w = tid >> 6;                  // wave 0..3 -> rows w*16..w*16+15
    int lane = tid & 63;
    int lr = lane & 15;
    int kh = lane >> 4;                // 0..3
    int r = w * 16 + lr;
    bf16x8 af[K / 32];
#pragma unroll
    for (int ka = 0; ka < K / 32; ++ka)
        af[ka] = *reinterpret_cast<const bf16x8*>(&Al[r * KP + ka * 32 + kh * 8]);
#pragma unroll
    for (int ct = 0; ct < NTOT / 16; ++ct) {
        int c = ct * 16 + lr;
        f32x4 acc = {0.f, 0.f, 0.f, 0.f};
#pragma unroll
        for (int ka = 0; ka < K / 32; ++ka) {
            bf16x8 bfr = *reinterpret_cast<const bf16x8*>(&Wl[c * KP + ka * 32 + kh * 8]);
            acc = __builtin_amdgcn_mfma_f32_16x16x32_bf16(af[ka], bfr, acc, 0, 0, 0);
        }
        size_t ob = (size_t)(row0 + w * 16 + kh * 4) * NTOT + ct * 16 + lr;
#pragma unroll
        for (int j = 0; j < 4; ++j)
            out[ob + (size_t)j * NTOT] = acc[j];
    }
}

// ---- x_proj with fused causal conv+SiLU ---------------------------------------
__global__ __launch_bounds__(256) void k_xproj(const float* __restrict__ xz,
                                               const float* __restrict__ W,
                                               const float* __restrict__ cw,
                                               const float* __restrict__ cb,
                                               float* __restrict__ xdbl) {
    constexpr int BM = 64, K = 128, BN = 36, TN = 3, TM = 4;
    constexpr int CT = BN / TN;   // 12
    constexpr int RT = BM / TM;   // 16
    constexpr int KP = K + 4;     // 132
    constexpr int WP = BN + 4;    // 40
    __shared__ float Xs[(BM + 3) * KP];
    __shared__ float Ws[K * WP];
    int tid = threadIdx.x;
    int row0 = blockIdx.x * BM;
    bool first = (row0 & 4095) == 0;
    for (int i = tid; i < BN * (K / 4); i += 256) {
        int k4 = i / BN;
        int c = i - k4 * BN;
        float4 w = *reinterpret_cast<const float4*>(&W[(size_t)c * K + k4 * 4]);
        Ws[(k4 * 4 + 0) * WP + c] = w.x;
        Ws[(k4 * 4 + 1) * WP + c] = w.y;
        Ws[(k4 * 4 + 2) * WP + c] = w.z;
        Ws[(k4 * 4 + 3) * WP + c] = w.w;
    }
    for (int i = tid; i < (BM + 3) * (K / 4); i += 256) {
        int r = i / (K / 4);
        int k4 = i - r * (K / 4);
        float4 v = {0, 0, 0, 0};
        if (!first || r >= 3)
            v = *reinterpret_cast<const float4*>(&xz[(size_t)(row0 - 3 + r) * 256 + k4 * 4]);
        *reinterpret_cast<float4*>(&Xs[r * KP + k4 * 4]) = v;
    }
    __syncthreads();
    {
        int rg = tid >> 5;
        int c0 = (tid & 31) * 4;
        float4 wr[4];
#pragma unroll
        for (int j = 0; j < 4; ++j)
            wr[j] = *reinterpret_cast<const float4*>(&cw[(c0 + j) * 4]);
        float4 cb4 = *reinterpret_cast<const float4*>(&cb[c0]);
        int R0 = rg * 8;
        float4 xr[11];
#pragma unroll
        for (int j = 0; j < 11; ++j)
            xr[j] = *reinterpret_cast<const float4*>(&Xs[(R0 + j) * KP + c0]);
        float4 ur[8];
#pragma unroll
        for (int j = 0; j < 8; ++j) {
            float4 acc;
            acc.x = cb4.x + wr[0].x * xr[j].x + wr[0].y * xr[j + 1].x + wr[0].z * xr[j + 2].x + wr[0].w * xr[j + 3].x;
            acc.y = cb4.y + wr[1].x * xr[j].y + wr[1].y * xr[j + 1].y + wr[1].z * xr[j + 2].y + wr[1].w * xr[j + 3].y;
            acc.z = cb4.z + wr[2].x * xr[j].z + wr[2].y * xr[j + 1].z + wr[2].z * xr[j + 2].z + wr[2].w * xr[j + 3].z;
            acc.w = cb4.w + wr[3].x * xr[j].w + wr[3].y * xr[j + 1].w + wr[3].z * xr[j + 2].w + wr[3].w * xr[j + 3].w;
            ur[j].x = silu_f(acc.x);
            ur[j].y = silu_f(acc.y);
            ur[j].z = silu_f(acc.z);
            ur[j].w = silu_f(acc.w);
        }
        __syncthreads();
#pragma unroll
        for (int j = 0; j < 8; ++j)
            *reinterpret_cast<float4*>(&Xs[(R0 + j) * KP + c0]) = ur[j];
    }
    __syncthreads();
    if (tid < CT * RT) {
        int ty = tid / CT, tx = tid - (tid / CT) * CT;
        int c0 = tx * TN;
        float acc[TM][TN];
#pragma unroll
        for (int i = 0; i < TM; ++i)
#pragma unroll
            for (int c = 0; c < TN; ++c) acc[i][c] = 0.f;
#pragma unroll 4
        for (int k = 0; k < K; k += 4) {
            float4 a[TM];
#pragma unroll
            for (int i = 0; i < TM; ++i)
                a[i] = *reinterpret_cast<const float4*>(&Xs[(ty + i * RT) * KP + k]);
            float bv[4][TN];
#pragma unroll
            for (int j = 0; j < 4; ++j)
#pragma unroll
                for (int c = 0; c < TN; ++c) bv[j][c] = Ws[(k + j) * WP + c0 + c];
#pragma unroll
            for (int i = 0; i < TM; ++i)
#pragma unroll
                for (int c = 0; c < TN; ++c)
                    acc[i][c] += a[i].x * bv[0][c] + a[i].y * bv[1][c]
                               + a[i].z * bv[2][c] + a[i].w * bv[3][c];
        }
#pragma unroll
        for (int i = 0; i < TM; ++i) {
            size_t o = (size_t)(row0 + ty + i * RT) * BN + c0;
#pragma unroll
            for (int c = 0; c < TN; ++c) xdbl[o + c] = acc[i][c];
        }
    }
}

// ---- helpers for the scan kernels --------------------------------------------
DEV bool load_a_struct(const float* Alog, int d, float4& a0v, float4& a1v,
                       float4& a2v, float4& a3v, float& a0) {
    const float4* al = reinterpret_cast<const float4*>(Alog + d * NS);
    float4 t0 = al[0], t1 = al[1], t2 = al[2], t3 = al[3];
    a0v.x = -__expf(t0.x); a0v.y = -__expf(t0.y); a0v.z = -__expf(t0.z); a0v.w = -__expf(t0.w);
    a1v.x = -__expf(t1.x); a1v.y = -__expf(t1.y); a1v.z = -__expf(t1.z); a1v.w = -__expf(t1.w);
    a2v.x = -__expf(t2.x); a2v.y = -__expf(t2.y); a2v.z = -__expf(t2.z); a2v.w = -__expf(t2.w);
    a3v.x = -__expf(t3.x); a3v.y = -__expf(t3.y); a3v.z = -__expf(t3.z); a3v.w = -__expf(t3.w);
    a0 = a0v.x;
    float aa[16] = {a0v.x, a0v.y, a0v.z, a0v.w, a1v.x, a1v.y, a1v.z, a1v.w,
                    a2v.x, a2v.y, a2v.z, a2v.w, a3v.x, a3v.y, a3v.z, a3v.w};
    bool fast = true;
#pragma unroll
    for (int n = 0; n < 16; ++n)
        fast = fast && (fabsf(aa[n] - a0 * (float)(n + 1)) <= 1e-4f * (float)(n + 1));
    return fast;
}

#define POWERS(dt, a0, D0, D1, D2, D3)                        \
    {                                                         \
        float E1 = __expf((dt) * (a0));                       \
        float E2 = E1 * E1, E3 = E2 * E1, E4 = E2 * E2;       \
        float E5 = E3 * E2, E6 = E3 * E3, E7 = E4 * E3;       \
        float E8 = E4 * E4, E9 = E5 * E4, E10 = E5 * E5;      \
        float E11 = E6 * E5, E12 = E6 * E6, E13 = E7 * E6;    \
        float E14 = E7 * E7, E15 = E8 * E7, E16 = E8 * E8;    \
        D0 = {E1, E2, E3, E4};                                \
        D1 = {E5, E6, E7, E8};                                \
        D2 = {E9, E10, E11, E12};                             \
        D3 = {E13, E14, E15, E16};                            \
    }

#define UPD4D(H, DA, BV)                          \
    H.x = DA.x * H.x + du * BV.x;                 \
    H.y = DA.y * H.y + du * BV.y;                 \
    H.z = DA.z * H.z + du * BV.z;                 \
    H.w = DA.w * H.w + du * BV.w;

#define UPD4E(H, A, BV)                                  \
    H.x = __expf(dt * A.x) * H.x + du * BV.x;            \
    H.y = __expf(dt * A.y) * H.y + du * BV.y;            \
    H.z = __expf(dt * A.z) * H.z + du * BV.z;            \
    H.w = __expf(dt * A.w) * H.w + du * BV.w;

#define CONV_WARMUP                                                     \
    float x3 = 0.f, x2 = 0.f, x1 = 0.f;                                 \
    if (c != 0) {                                                       \
        size_t wb = ((size_t)b * HW + t0) * 256 + d;                    \
        x3 = xz[wb - 3 * 256];                                          \
        x2 = xz[wb - 2 * 256];                                          \
        x1 = xz[wb - 1 * 256];                                          \
    }

#define CONV_STEP(base)                                                 \
    float xv = xz[(base) * 256 + d];                                    \
    float cacc = cbv + cwv.x * x3 + cwv.y * x2 + cwv.z * x1 + cwv.w * xv; \
    float uu = cacc * sigmoid_f(cacc);                                  \
    x3 = x2; x2 = x1; x1 = xv;

// ---------------- scan pass 1: per-chunk local scan (h0 = 0) -------------------
__global__ __launch_bounds__(128, 4) void k_scan1(const float* __restrict__ xz,
                                                  const float* __restrict__ xdbl,
                                                  const float* __restrict__ dpw,
                                                  const float* __restrict__ dpb,
                                                  const float* __restrict__ Alog,
                                                  const float* __restrict__ cw,
                                                  const float* __restrict__ cb,
                                                  float* __restrict__ cS,
                                                  float* __restrict__ cDT) {
    int blk = blockIdx.x;
    int b = blk / NC;
    int c = blk % NC;
    int d = threadIdx.x;
    float4 a0v, a1v, a2v, a3v;
    float a0;
    bool fast = load_a_struct(Alog, d, a0v, a1v, a2v, a3v, a0);
    float4 w = *reinterpret_cast<const float4*>(dpw + d * 4);
    float bb = dpb[d];
    float4 cwv = *reinterpret_cast<const float4*>(cw + d * 4);
    float cbv = cb[d];
    float4 h0 = {0, 0, 0, 0}, h1 = {0, 0, 0, 0}, h2 = {0, 0, 0, 0}, h3 = {0, 0, 0, 0};
    float sdt = 0.f;
    int t0 = c * CS;
    CONV_WARMUP
    if (fast) {
        for (int tt = 0; tt < CS; ++tt) {
            size_t base = (size_t)b * HW + t0 + tt;
            const float4* xd4 = reinterpret_cast<const float4*>(xdbl + base * 36);
            float4 x0 = xd4[0];
            float4 B0 = xd4[1], B1 = xd4[2], B2 = xd4[3], B3 = xd4[4];
            float dt = softplus_f(w.x * x0.x + w.y * x0.y + w.z * x0.z + w.w * x0.w + bb);
            CONV_STEP(base)
            float du = dt * uu;
            sdt += dt;
            float4 D0, D1, D2, D3;
            POWERS(dt, a0, D0, D1, D2, D3)
            UPD4D(h0, D0, B0) UPD4D(h1, D1, B1) UPD4D(h2, D2, B2) UPD4D(h3, D3, B3)
        }
    } else {
        for (int tt = 0; tt < CS; ++tt) {
            size_t base = (size_t)b * HW + t0 + tt;
            const float4* xd4 = reinterpret_cast<const float4*>(xdbl + base * 36);
            float4 x0 = xd4[0];
            float4 B0 = xd4[1], B1 = xd4[2], B2 = xd4[3], B3 = xd4[4];
            float dt = softplus_f(w.x * x0.x + w.y * x0.y + w.z * x0.z + w.w * x0.w + bb);
            CONV_STEP(base)
            float du = dt * uu;
            sdt += dt;
            UPD4E(h0, a0v, B0) UPD4E(h1, a1v, B1) UPD4E(h2, a2v, B2) UPD4E(h3, a3v, B3)
        }
    }
    size_t o = (size_t)blk * DI + d;
    cDT[o] = sdt;
    float4* cs4 = reinterpret_cast<float4*>(cS + o * NS);
    cs4[0] = h0; cs4[1] = h1; cs4[2] = h2; cs4[3] = h3;
}

// ------ scan pass 2: sequential chunk combine per (b,d,n), IN PLACE on cS ------
__global__ __launch_bounds__(256) void k_scan2(float* __restrict__ cS,
                                               const float* __restrict__ cDT,
                                               const float* __restrict__ Alog) {
    int idx = blockIdx.x * 256 + threadIdx.x;
    if (idx >= Bn * DI * NS) return;
    int n = idx & 15;
    int d = (idx >> 4) & 127;
    int b = idx >> 11;
    float a = -__expf(Alog[d * NS + n]);
    float h = 0.f;
    for (int c = 0; c < NC; ++c) {
        size_t o = (size_t)(b * NC + c) * DI + d;
        float s = cS[o * NS + n];
        cS[o * NS + n] = h;
        h = __expf(a * cDT[o]) * h + s;
    }
}

// ------- scan pass 3: re-scan with proper h0, emit gated y into uy -------------
__global__ __launch_bounds__(128, 4) void k_scan3(float* __restrict__ uy,
                                                  const float* __restrict__ xz,
                                                  const float* __restrict__ xdbl,
                                                  const float* __restrict__ dpw,
                                                  const float* __restrict__ dpb,
                                                  const float* __restrict__ Alog,
                                                  const float* __restrict__ Dp,
                                                  const float* __restrict__ cw,
                                                  const float* __restrict__ cb,
                                                  const float* __restrict__ iS) {
    int blk = blockIdx.x;
    int b = blk / NC;
    int c = blk % NC;
    int d = threadIdx.x;
    float4 a0v, a1v, a2v, a3v;
    float a0;
    bool fast = load_a_struct(Alog, d, a0v, a1v, a2v, a3v, a0);
    float4 w = *reinterpret_cast<const float4*>(dpw + d * 4);
    float bb = dpb[d];
    float Dv = Dp[d];
    float4 cwv = *reinterpret_cast<const float4*>(cw + d * 4);
    float cbv = cb[d];
    size_t so = (size_t)blk * DI + d;
    const float4* is4 = reinterpret_cast<const float4*>(iS + so * NS);
    float4 h0 = is4[0], h1 = is4[1], h2 = is4[2], h3 = is4[3];
    int t0 = c * CS;
    CONV_WARMUP
    if (fast) {
        for (int tt = 0; tt < CS; ++tt) {
            size_t base = (size_t)b * HW + t0 + tt;
            const float4* xd4 = reinterpret_cast<const float4*>(xdbl + base * 36);
            float4 x0 = xd4[0];
            float4 B0 = xd4[1], B1 = xd4[2], B2 = xd4[3], B3 = xd4[4];
            float4 C0 = xd4[5], C1 = xd4[6], C2 = xd4[7], C3 = xd4[8];
            float dt = softplus_f(w.x * x0.x + w.y * x0.y + w.z * x0.z + w.w * x0.w + bb);
            CONV_STEP(base)
            float du = dt * uu;
            float4 D0, D1, D2, D3;
            POWERS(dt, a0, D0, D1, D2, D3)
            UPD4D(h0, D0, B0) UPD4D(h1, D1, B1) UPD4D(h2, D2, B2) UPD4D(h3, D3, B3)
            float y = h0.x * C0.x + h0.y * C0.y + h0.z * C0.z + h0.w * C0.w
                    + h1.x * C1.x + h1.y * C1.y + h1.z * C1.z + h1.w * C1.w
                    + h2.x * C2.x + h2.y * C2.y + h2.z * C2.z + h2.w * C2.w
                    + h3.x * C3.x + h3.y * C3.y + h3.z * C3.z + h3.w * C3.w;
            y += uu * Dv;
            float zz = xz[base * 256 + 128 + d];
            y *= zz * sigmoid_f(zz);
            uy[base * DI + d] = y;
        }
    } else {
        for (int tt = 0; tt < CS; ++tt) {
            size_t base = (size_t)b * HW + t0 + tt;
            const float4* xd4 = reinterpret_cast<const float4*>(xdbl + base * 36);
            float4 x0 = xd4[0];
            float4 B0 = xd4[1], B1 = xd4[2], B2 = xd4[3], B3 = xd4[4];
            float4 C0 = xd4[5], C1 = xd4[6], C2 = xd4[7], C3 = xd4[8];
            float dt = softplus_f(w.x * x0.x + w.y * x0.y + w.z * x0.z + w.w * x0.w + bb);
            CONV_STEP(base)
            float du = dt * uu;
            UPD4E(h0, a0v, B0) UPD4E(h1, a1v, B1) UPD4E(h2, a2v, B2) UPD4E(h3, a3v, B3)
            float y = h0.x * C0.x + h0.y * C0.y + h0.z * C0.z + h0.w * C0.w
                    + h1.x * C1.x + h1.y * C1.y + h1.z * C1.z + h1.w * C1.w
                    + h2.x * C2.x + h2.y * C2.y + h2.z * C2.z + h2.w * C2.w
                    + h3.x * C3.x + h3.y * C3.y + h3.z * C3.z + h3.w * C3.w;
            y += uu * Dv;
            float zz = xz[base * 256 + 128 + d];
            y *= zz * sigmoid_f(zz);
            uy[base * DI + d] = y;
        }
    }
}

// ------- head with fused LN2 + residual: out = z - (LN(feat) @ head_w.T + hb) ---
__global__ __launch_bounds__(256) void k_head(const float* __restrict__ feat,
                                              const float* __restrict__ hwt,
                                              const float* __restrict__ hb,
                                              const float* __restrict__ g,
                                              const float* __restrict__ bta,
                                              const float* __restrict__ z,
                                              float* __restrict__ out) {
    __shared__ float fl[64 * 65];
    int row0 = blockIdx.x * 64;
    for (int i = threadIdx.x; i < 64 * 64; i += 256) {
        int r = i >> 6;
        int m = i & 63;
        fl[r * 65 + m] = feat[(size_t)(row0 + r) * 64 + m];
    }
    __syncthreads();
    int r = threadIdx.x >> 2;
    int c = threadIdx.x & 3;
    int m0 = c * 16;
    float s = 0.f;
#pragma unroll
    for (int mi = 0; mi < 16; ++mi) s += fl[r * 65 + m0 + mi];
    s += __shfl_xor(s, 1, 64);
    s += __shfl_xor(s, 2, 64);
    float mu = s * (1.f / 64.f);
    float v = 0.f;
#pragma unroll
    for (int mi = 0; mi < 16; ++mi) {
        float dd = fl[r * 65 + m0 + mi] - mu;
        v += dd * dd;
    }
    v += __shfl_xor(v, 1, 64);
    v += __shfl_xor(v, 2, 64);
    float rs = rsqrtf(v * (1.f / 64.f) + 1e-5f);
#pragma unroll
    for (int mi = 0; mi < 16; ++mi) {
        int m = m0 + mi;
        float x = fl[r * 65 + m];
        fl[r * 65 + m] = (x - mu) * rs * g[m] + bta[m];
    }
    __syncthreads();
    float acc = hb[c];
#pragma unroll
    for (int m = 0; m < 64; ++m) acc += fl[r * 65 + m] * hwt[c * 64 + m];
    int bl = row0 + r;
    int b = bl >> 12;
    int hw = bl & 4095;
    size_t o = ((size_t)b * 4 + c) * HW + hw;
    out[o] = z[o] - acc;
}

// -------------------------------------------------------------------------------
static void run_mamba(const float* const* P, float* feat, float* xz, float* u,
                      float* xdbl, float* cS, float* cDT, hipStream_t s) {
    // P: 0 in_proj_w, 1 conv_w, 2 conv_b, 3 x_proj_w, 4 dt_proj_w, 5 dt_proj_b,
    //    6 A_log, 7 D, 8 out_proj_w
    k_gemm_mfma<64, 256><<<BL / 64, 256, 0, s>>>(feat, P[0], xz);
    k_xproj<<<BL / 64, 256, 0, s>>>(xz, P[3], P[1], P[2], xdbl);
    k_scan1<<<Bn * NC, DI, 0, s>>>(xz, xdbl, P[4], P[5], P[6], P[1], P[2], cS, cDT);
    k_scan2<<<(Bn * DI * NS) / 256, 256, 0, s>>>(cS, cDT, P[6]);
    k_scan3<<<Bn * NC, DI, 0, s>>>(u, xz, xdbl, P[4], P[5], P[6], P[7], P[1], P[2], cS);
    k_gemm_mfma<128, 64><<<BL / 64, 256, 0, s>>>(u, P[8], feat);
}

extern "C" void kernel_launch(void* const* d_in, const int* in_sizes, int n_in,
                              void* d_out, int out_size, void* d_ws, size_t ws_size,
                              hipStream_t stream) {
    const float* z = (const float*)d_in[0];
    const float* ew = (const float*)d_in[1];
    const float* eb = (const float*)d_in[2];
    const float* m1[9];
    const float* m2[9];
    for (int i = 0; i < 9; ++i) m1[i] = (const float*)d_in[3 + i];
    for (int i = 0; i < 9; ++i) m2[i] = (const float*)d_in[12 + i];
    const float* ln1g = (const float*)d_in[21];
    const float* ln1b = (const float*)d_in[22];
    const float* ln2g = (const float*)d_in[23];
    const float* ln2b = (const float*)d_in[24];
    const float* hwt = (const float*)d_in[25];
    const float* hb = (const float*)d_in[26];

    float* ws = (float*)d_ws;
    float* feat = ws;                         // BL*64
    float* xz = feat + (size_t)BL * 64;       // BL*256
    float* u = xz + (size_t)BL * 256;         // BL*128
    float* xdbl = u + (size_t)BL * 128;       // BL*36
    float* cS = xdbl + (size_t)BL * 36;       // Bn*NC*DI*NS
    float* cDT = cS + (size_t)Bn * NC * DI * NS;  // Bn*NC*DI

    k_embed<<<(BL * DM) / 256, 256, 0, stream>>>(z, ew, eb, feat);
    run_mamba(m1, feat, xz, u, xdbl, cS, cDT, stream);
    k_ln<<<4096, 256, 0, stream>>>(feat, ln1g, ln1b, BL);
    run_mamba(m2, feat, xz, u, xdbl, cS, cDT, stream);
    // LN2 is fused inside k_head — no standalone k_ln here (round-14 bug: double LN).
    k_head<<<BL / 64, 256, 0, stream>>>(feat, hwt, hb, ln2g, ln2b, z, (float*)d_out);
}